// Round 1
// baseline (533.255 us; speedup 1.0000x reference)
//
#include <hip/hip_runtime.h>
#include <hip/hip_bf16.h>
#include <stdint.h>

#define NROWS 8192
#define DIM   768
#define NTILE 64          // 8192/128
#define EPSV  1e-6f

typedef __attribute__((ext_vector_type(8))) short short8;
typedef __attribute__((ext_vector_type(4))) float f32x4;

__device__ __forceinline__ ushort f2bf(float f) {
    union { float f; uint32_t u; } x; x.f = f;
    uint32_t r = x.u + 0x7fffu + ((x.u >> 16) & 1u);
    return (ushort)(r >> 16);
}
__device__ __forceinline__ uint32_t pk2(float a, float b) {
    return (uint32_t)f2bf(a) | ((uint32_t)f2bf(b) << 16);
}

// ---------------- row stats: sx = sum(x^2), rx = sum(x) ----------------
__global__ __launch_bounds__(256)
void row_stats(const float* __restrict__ X, const float* __restrict__ Y,
               float* __restrict__ stats) {
    int row = blockIdx.x;                  // 0..16383
    bool isX = row < NROWS;
    int r = isX ? row : row - NROWS;
    const float* p = (isX ? X : Y) + (size_t)r * DIM;
    int t = threadIdx.x;
    float v0 = p[t], v1 = p[t + 256], v2 = p[t + 512];
    float s = v0 + v1 + v2;
    float q = v0*v0 + v1*v1 + v2*v2;
    #pragma unroll
    for (int o = 32; o; o >>= 1) { s += __shfl_down(s, o); q += __shfl_down(q, o); }
    __shared__ float sh[8];
    int wave = t >> 6, lane = t & 63;
    if (lane == 0) { sh[wave] = s; sh[4 + wave] = q; }
    __syncthreads();
    if (t == 0) {
        float ss = sh[0]+sh[1]+sh[2]+sh[3];
        float qq = sh[4]+sh[5]+sh[6]+sh[7];
        float* sx = stats;                 // sum of squares, X
        float* rx = stats + NROWS;         // sum, X
        float* sy = stats + 2*NROWS;       // sum of squares, Y
        float* ry = stats + 3*NROWS;       // sum, Y
        if (isX) { sx[r] = qq; rx[r] = ss; } else { sy[r] = qq; ry[r] = ss; }
    }
}

// ---------------- fused GEMM + loss epilogue ----------------
// 128x128 tile, 4 waves (2x2), each wave 64x64 = 4x4 frags of 16x16.
// JJ: A=X,B=X, only i<j elements; accumulate pos (d2), neg (relu(1-d)^2), cnt.
// JN: A=X,B=Y, all elements; accumulate cross.
template<bool JJ>
__global__ __launch_bounds__(256)
void gemm_loss(const float* __restrict__ A, const float* __restrict__ B,
               const int* __restrict__ labels,
               const float* __restrict__ sA, const float* __restrict__ rA,
               const float* __restrict__ sB, const float* __restrict__ rB,
               float4* __restrict__ partials) {
    const int ti = blockIdx.y, tj = blockIdx.x;
    const int slot = ti * gridDim.x + tj;
    const int t = threadIdx.x;

    if (JJ && ti > tj) {                   // lower triangle: no work
        if (t == 0) partials[slot] = float4{0.f, 0.f, 0.f, 0.f};
        return;
    }

    __shared__ ushort Asm[128][40];        // padded: 80B row stride
    __shared__ ushort Bsm[128][40];
    __shared__ float red[4][4];

    const int wave = t >> 6, lane = t & 63;
    const int wr = wave >> 1, wc = wave & 1;
    const int i0 = ti * 128, j0 = tj * 128;

    f32x4 acc[4][4] = {};

    const int sr = t >> 1;                 // staging row 0..127
    const int sh = (t & 1) * 16;           // staging col offset (floats)
    const float* pa = A + (size_t)(i0 + sr) * DIM + sh;
    const float* pb = B + (size_t)(j0 + sr) * DIM + sh;

    const int mrow = lane & 15;
    const int kcol = (lane >> 4) * 8;

    #pragma unroll 1
    for (int k0 = 0; k0 < DIM; k0 += 32) {
        float fa[16], fb[16];
        #pragma unroll
        for (int u = 0; u < 4; ++u) {
            *(float4*)(fa + 4*u) = *(const float4*)(pa + k0 + 4*u);
            *(float4*)(fb + 4*u) = *(const float4*)(pb + k0 + 4*u);
        }
        __syncthreads();                   // previous compute done reading LDS
        uint4 WA0, WA1, WB0, WB1;
        WA0.x = pk2(fa[0],fa[1]);  WA0.y = pk2(fa[2],fa[3]);
        WA0.z = pk2(fa[4],fa[5]);  WA0.w = pk2(fa[6],fa[7]);
        WA1.x = pk2(fa[8],fa[9]);  WA1.y = pk2(fa[10],fa[11]);
        WA1.z = pk2(fa[12],fa[13]);WA1.w = pk2(fa[14],fa[15]);
        WB0.x = pk2(fb[0],fb[1]);  WB0.y = pk2(fb[2],fb[3]);
        WB0.z = pk2(fb[4],fb[5]);  WB0.w = pk2(fb[6],fb[7]);
        WB1.x = pk2(fb[8],fb[9]);  WB1.y = pk2(fb[10],fb[11]);
        WB1.z = pk2(fb[12],fb[13]);WB1.w = pk2(fb[14],fb[15]);
        *(uint4*)&Asm[sr][sh]     = WA0;
        *(uint4*)&Asm[sr][sh + 8] = WA1;
        *(uint4*)&Bsm[sr][sh]     = WB0;
        *(uint4*)&Bsm[sr][sh + 8] = WB1;
        __syncthreads();

        short8 afr[4], bfr[4];
        #pragma unroll
        for (int mi = 0; mi < 4; ++mi)
            afr[mi] = *(const short8*)&Asm[wr*64 + mi*16 + mrow][kcol];
        #pragma unroll
        for (int ni = 0; ni < 4; ++ni)
            bfr[ni] = *(const short8*)&Bsm[wc*64 + ni*16 + mrow][kcol];
        #pragma unroll
        for (int mi = 0; mi < 4; ++mi)
            #pragma unroll
            for (int ni = 0; ni < 4; ++ni)
                acc[mi][ni] = __builtin_amdgcn_mfma_f32_16x16x32_bf16(
                    afr[mi], bfr[ni], acc[mi][ni], 0, 0, 0);
    }

    // -------- epilogue --------
    const int ibase = i0 + wr*64 + ((lane >> 4) << 2);  // + mi*16 + reg
    const int jbase = j0 + wc*64 + (lane & 15);          // + ni*16

    float sxv[4][4], rxv[4][4];
    int   labi[4][4];
    float syv[4], ryv[4];
    int   labj[4];
    #pragma unroll
    for (int mi = 0; mi < 4; ++mi)
        #pragma unroll
        for (int r = 0; r < 4; ++r) {
            int gi = ibase + mi*16 + r;
            sxv[mi][r] = sA[gi]; rxv[mi][r] = rA[gi];
            if (JJ) labi[mi][r] = labels[gi];
        }
    #pragma unroll
    for (int ni = 0; ni < 4; ++ni) {
        int gj = jbase + ni*16;
        syv[ni] = sB[gj]; ryv[ni] = rB[gj];
        if (JJ) labj[ni] = labels[gj];
    }

    const float deps = (float)DIM * EPSV * EPSV;
    float pos = 0.f, neg = 0.f, cross = 0.f, cnt = 0.f;
    #pragma unroll
    for (int mi = 0; mi < 4; ++mi)
        #pragma unroll
        for (int ni = 0; ni < 4; ++ni)
            #pragma unroll
            for (int r = 0; r < 4; ++r) {
                float g  = acc[mi][ni][r];
                float d2 = sxv[mi][r] + syv[ni] - 2.f*g
                         + 2.f*EPSV*(rxv[mi][r] - ryv[ni]) + deps;
                d2 = fmaxf(d2, 0.f);
                if (JJ) {
                    int gi = ibase + mi*16 + r;
                    int gj = jbase + ni*16;
                    if (gi < gj) {
                        if (labi[mi][r] == labj[ni]) { pos += d2; cnt += 1.f; }
                        else {
                            float dist = sqrtf(fmaxf(d2, 1e-12f));
                            float tt = fmaxf(1.f - dist, 0.f);
                            neg += tt*tt;
                        }
                    }
                } else {
                    float dist = sqrtf(fmaxf(d2, 1e-12f));
                    float tt = fmaxf(1.f - dist, 0.f);
                    cross += tt*tt;
                }
            }

    #pragma unroll
    for (int o = 32; o; o >>= 1) {
        pos   += __shfl_down(pos, o);
        neg   += __shfl_down(neg, o);
        cross += __shfl_down(cross, o);
        cnt   += __shfl_down(cnt, o);
    }
    if (lane == 0) { red[wave][0] = pos; red[wave][1] = neg;
                     red[wave][2] = cross; red[wave][3] = cnt; }
    __syncthreads();
    if (t == 0) {
        float4 v;
        v.x = red[0][0]+red[1][0]+red[2][0]+red[3][0];
        v.y = red[0][1]+red[1][1]+red[2][1]+red[3][1];
        v.z = red[0][2]+red[1][2]+red[2][2]+red[3][2];
        v.w = red[0][3]+red[1][3]+red[2][3]+red[3][3];
        partials[slot] = v;
    }
}

// ---------------- final reduce ----------------
__global__ __launch_bounds__(256)
void finalize_kernel(const float4* __restrict__ partials, float* __restrict__ out) {
    int t = threadIdx.x;
    double p = 0, n = 0, c = 0, k = 0;
    for (int s = t; s < 2 * NTILE * NTILE; s += 256) {
        float4 v = partials[s];
        p += v.x; n += v.y; c += v.z; k += v.w;
    }
    __shared__ double sh[256][4];
    sh[t][0] = p; sh[t][1] = n; sh[t][2] = c; sh[t][3] = k;
    __syncthreads();
    for (int o = 128; o; o >>= 1) {
        if (t < o) {
            sh[t][0] += sh[t+o][0]; sh[t][1] += sh[t+o][1];
            sh[t][2] += sh[t+o][2]; sh[t][3] += sh[t+o][3];
        }
        __syncthreads();
    }
    if (t == 0) {
        double npos = sh[0][3] < 1.0 ? 1.0 : sh[0][3];
        double total = (double)NROWS * (NROWS - 1) * 0.5;
        double nneg = total - sh[0][3]; if (nneg < 1.0) nneg = 1.0;
        double loss = sh[0][0] / npos + sh[0][1] / nneg
                    + sh[0][2] / ((double)NROWS * (double)NROWS);
        out[0] = (float)loss;
    }
}

extern "C" void kernel_launch(void* const* d_in, const int* in_sizes, int n_in,
                              void* d_out, int out_size, void* d_ws, size_t ws_size,
                              hipStream_t stream) {
    const float* X      = (const float*)d_in[0];
    const float* Y      = (const float*)d_in[1];
    const int*   labels = (const int*)d_in[2];
    float* out = (float*)d_out;
    char*  ws  = (char*)d_ws;

    float4* partials = (float4*)ws;                       // 2*64*64*16B = 128KB
    float*  stats    = (float*)(ws + 2*NTILE*NTILE*sizeof(float4)); // 4*8192*4B = 128KB

    row_stats<<<2 * NROWS, 256, 0, stream>>>(X, Y, stats);

    dim3 grid(NTILE, NTILE);
    gemm_loss<true><<<grid, 256, 0, stream>>>(
        X, X, labels, stats, stats + NROWS, stats, stats + NROWS, partials);
    gemm_loss<false><<<grid, 256, 0, stream>>>(
        X, Y, labels, stats, stats + NROWS, stats + 2*NROWS, stats + 3*NROWS,
        partials + NTILE*NTILE);

    finalize_kernel<<<1, 256, 0, stream>>>(partials, out);
}

// Round 2
// 370.821 us; speedup vs baseline: 1.4380x; 1.4380x over previous
//
#include <hip/hip_runtime.h>
#include <hip/hip_bf16.h>
#include <stdint.h>

#define NROWS 8192
#define DIM   768
#define NTILE 64          // 8192/128
#define EPSV  1e-6f

typedef __attribute__((ext_vector_type(8))) short short8;
typedef __attribute__((ext_vector_type(4))) float f32x4;

__device__ __forceinline__ ushort f2bf(float f) {
    union { float f; uint32_t u; } x; x.f = f;
    uint32_t r = x.u + 0x7fffu + ((x.u >> 16) & 1u);
    return (ushort)(r >> 16);
}

// async global->LDS, 16B per lane; LDS dest is wave-uniform base (+lane*16 by HW)
__device__ __forceinline__ void gload16(const void* g, void* l) {
    __builtin_amdgcn_global_load_lds(
        (const __attribute__((address_space(1))) void*)g,
        (__attribute__((address_space(3))) void*)l,
        16, 0, 0);
}

// ------------- prep: row stats (fp32 exact) + bf16 conversion -------------
__global__ __launch_bounds__(256)
void prep(const float* __restrict__ X, const float* __restrict__ Y,
          float* __restrict__ stats,
          ushort* __restrict__ Xbf, ushort* __restrict__ Ybf) {
    int row = blockIdx.x;                  // 0..16383
    bool isX = row < NROWS;
    int r = isX ? row : row - NROWS;
    const float* p = (isX ? X : Y) + (size_t)r * DIM;
    ushort* q = (isX ? Xbf : Ybf) + (size_t)r * DIM;
    int t = threadIdx.x;
    float v0 = p[t], v1 = p[t + 256], v2 = p[t + 512];
    q[t] = f2bf(v0); q[t + 256] = f2bf(v1); q[t + 512] = f2bf(v2);
    float s = v0 + v1 + v2;
    float qs = v0*v0 + v1*v1 + v2*v2;
    #pragma unroll
    for (int o = 32; o; o >>= 1) { s += __shfl_down(s, o); qs += __shfl_down(qs, o); }
    __shared__ float sh[8];
    int wave = t >> 6, lane = t & 63;
    if (lane == 0) { sh[wave] = s; sh[4 + wave] = qs; }
    __syncthreads();
    if (t == 0) {
        float ss = sh[0]+sh[1]+sh[2]+sh[3];
        float qq = sh[4]+sh[5]+sh[6]+sh[7];
        if (isX) { stats[r] = qq; stats[NROWS + r] = ss; }
        else     { stats[2*NROWS + r] = qq; stats[3*NROWS + r] = ss; }
    }
}

// ------------- fused GEMM (m97 structure) + loss epilogue -------------
// 128x128 tile, 4 waves (2x2), each wave 64x64 = 4x4 frags of 16x16, BK=32.
template<bool JJ>
__global__ __launch_bounds__(256)
void gemm_loss(const ushort* __restrict__ A, const ushort* __restrict__ B,
               const int* __restrict__ labels,
               const float* __restrict__ sA, const float* __restrict__ rA,
               const float* __restrict__ sB, const float* __restrict__ rB,
               float4* __restrict__ partials) {
    const int ti = blockIdx.y, tj = blockIdx.x;
    const int slot = ti * gridDim.x + tj;
    const int t = threadIdx.x;

    if (JJ && ti > tj) {                   // lower triangle: no work
        if (t == 0) partials[slot] = float4{0.f, 0.f, 0.f, 0.f};
        return;
    }

    // linear layout [128][32] bf16 (64B rows) — required by global_load_lds
    __shared__ __align__(16) ushort Asm[128 * 32];
    __shared__ __align__(16) ushort Bsm[128 * 32];
    __shared__ float red[4][4];

    const int wave = t >> 6, lane = t & 63;
    const int wr = wave >> 1, wc = wave & 1;
    const int i0 = ti * 128, j0 = tj * 128;

    // staging map: chunk q = c*4+wave covers LDS bytes [q*1024, q*1024+1024)
    // = rows q*16..q*16+15; lane l -> row q*16+(l>>2), col (l&3)*8 (elems)
    const int grow = wave * 16 + (lane >> 2);
    const int gcol = (lane & 3) * 8;
    const ushort* pa0 = A + (size_t)(i0 + grow)      * DIM + gcol;
    const ushort* pa1 = A + (size_t)(i0 + grow + 64) * DIM + gcol;
    const ushort* pb0 = B + (size_t)(j0 + grow)      * DIM + gcol;
    const ushort* pb1 = B + (size_t)(j0 + grow + 64) * DIM + gcol;
    ushort* la0 = Asm + wave * 512;        // q=wave
    ushort* la1 = Asm + (4 + wave) * 512;  // q=4+wave
    ushort* lb0 = Bsm + wave * 512;
    ushort* lb1 = Bsm + (4 + wave) * 512;

    const int mrow = lane & 15;
    const int kcol = (lane >> 4) * 8;

    f32x4 acc[4][4] = {};

    #pragma unroll 1
    for (int k0 = 0; k0 < DIM; k0 += 32) {
        __syncthreads();                   // prev compute done reading LDS
        gload16(pa0 + k0, la0);
        gload16(pa1 + k0, la1);
        gload16(pb0 + k0, lb0);
        gload16(pb1 + k0, lb1);
        __syncthreads();                   // compiler drains vmcnt before barrier

        short8 afr[4], bfr[4];
        #pragma unroll
        for (int mi = 0; mi < 4; ++mi)
            afr[mi] = *(const short8*)(Asm + (wr*64 + mi*16 + mrow) * 32 + kcol);
        #pragma unroll
        for (int ni = 0; ni < 4; ++ni)
            bfr[ni] = *(const short8*)(Bsm + (wc*64 + ni*16 + mrow) * 32 + kcol);
        #pragma unroll
        for (int mi = 0; mi < 4; ++mi)
            #pragma unroll
            for (int ni = 0; ni < 4; ++ni)
                acc[mi][ni] = __builtin_amdgcn_mfma_f32_16x16x32_bf16(
                    afr[mi], bfr[ni], acc[mi][ni], 0, 0, 0);
    }

    // -------- epilogue (verified round 0, unchanged) --------
    const int ibase = i0 + wr*64 + ((lane >> 4) << 2);  // + mi*16 + reg
    const int jbase = j0 + wc*64 + (lane & 15);          // + ni*16

    float sxv[4][4], rxv[4][4];
    int   labi[4][4];
    float syv[4], ryv[4];
    int   labj[4];
    #pragma unroll
    for (int mi = 0; mi < 4; ++mi)
        #pragma unroll
        for (int r = 0; r < 4; ++r) {
            int gi = ibase + mi*16 + r;
            sxv[mi][r] = sA[gi]; rxv[mi][r] = rA[gi];
            if (JJ) labi[mi][r] = labels[gi];
        }
    #pragma unroll
    for (int ni = 0; ni < 4; ++ni) {
        int gj = jbase + ni*16;
        syv[ni] = sB[gj]; ryv[ni] = rB[gj];
        if (JJ) labj[ni] = labels[gj];
    }

    const float deps = (float)DIM * EPSV * EPSV;
    float pos = 0.f, neg = 0.f, cross = 0.f, cnt = 0.f;
    #pragma unroll
    for (int mi = 0; mi < 4; ++mi)
        #pragma unroll
        for (int ni = 0; ni < 4; ++ni)
            #pragma unroll
            for (int r = 0; r < 4; ++r) {
                float g  = acc[mi][ni][r];
                float d2 = sxv[mi][r] + syv[ni] - 2.f*g
                         + 2.f*EPSV*(rxv[mi][r] - ryv[ni]) + deps;
                d2 = fmaxf(d2, 0.f);
                if (JJ) {
                    int gi = ibase + mi*16 + r;
                    int gj = jbase + ni*16;
                    if (gi < gj) {
                        if (labi[mi][r] == labj[ni]) { pos += d2; cnt += 1.f; }
                        else {
                            float dist = sqrtf(fmaxf(d2, 1e-12f));
                            float tt = fmaxf(1.f - dist, 0.f);
                            neg += tt*tt;
                        }
                    }
                } else {
                    float dist = sqrtf(fmaxf(d2, 1e-12f));
                    float tt = fmaxf(1.f - dist, 0.f);
                    cross += tt*tt;
                }
            }

    #pragma unroll
    for (int o = 32; o; o >>= 1) {
        pos   += __shfl_down(pos, o);
        neg   += __shfl_down(neg, o);
        cross += __shfl_down(cross, o);
        cnt   += __shfl_down(cnt, o);
    }
    if (lane == 0) { red[wave][0] = pos; red[wave][1] = neg;
                     red[wave][2] = cross; red[wave][3] = cnt; }
    __syncthreads();
    if (t == 0) {
        float4 v;
        v.x = red[0][0]+red[1][0]+red[2][0]+red[3][0];
        v.y = red[0][1]+red[1][1]+red[2][1]+red[3][1];
        v.z = red[0][2]+red[1][2]+red[2][2]+red[3][2];
        v.w = red[0][3]+red[1][3]+red[2][3]+red[3][3];
        partials[slot] = v;
    }
}

// ---------------- final reduce ----------------
__global__ __launch_bounds__(256)
void finalize_kernel(const float4* __restrict__ partials, float* __restrict__ out) {
    int t = threadIdx.x;
    double p = 0, n = 0, c = 0, k = 0;
    for (int s = t; s < 2 * NTILE * NTILE; s += 256) {
        float4 v = partials[s];
        p += v.x; n += v.y; c += v.z; k += v.w;
    }
    __shared__ double sh[256][4];
    sh[t][0] = p; sh[t][1] = n; sh[t][2] = c; sh[t][3] = k;
    __syncthreads();
    for (int o = 128; o; o >>= 1) {
        if (t < o) {
            sh[t][0] += sh[t+o][0]; sh[t][1] += sh[t+o][1];
            sh[t][2] += sh[t+o][2]; sh[t][3] += sh[t+o][3];
        }
        __syncthreads();
    }
    if (t == 0) {
        double npos = sh[0][3] < 1.0 ? 1.0 : sh[0][3];
        double total = (double)NROWS * (NROWS - 1) * 0.5;
        double nneg = total - sh[0][3]; if (nneg < 1.0) nneg = 1.0;
        double loss = sh[0][0] / npos + sh[0][1] / nneg
                    + sh[0][2] / ((double)NROWS * (double)NROWS);
        out[0] = (float)loss;
    }
}

extern "C" void kernel_launch(void* const* d_in, const int* in_sizes, int n_in,
                              void* d_out, int out_size, void* d_ws, size_t ws_size,
                              hipStream_t stream) {
    const float* X      = (const float*)d_in[0];
    const float* Y      = (const float*)d_in[1];
    const int*   labels = (const int*)d_in[2];
    float* out = (float*)d_out;
    char*  ws  = (char*)d_ws;

    // ws layout: partials (128KB) | stats (128KB) | Xbf (12.6MB) | Ybf (12.6MB)
    float4* partials = (float4*)ws;
    float*  stats    = (float*)(ws + 2*NTILE*NTILE*sizeof(float4));
    ushort* Xbf      = (ushort*)(ws + 256*1024);
    ushort* Ybf      = Xbf + (size_t)NROWS * DIM;

    prep<<<2 * NROWS, 256, 0, stream>>>(X, Y, stats, Xbf, Ybf);

    dim3 grid(NTILE, NTILE);
    gemm_loss<true><<<grid, 256, 0, stream>>>(
        Xbf, Xbf, labels, stats, stats + NROWS, stats, stats + NROWS, partials);
    gemm_loss<false><<<grid, 256, 0, stream>>>(
        Xbf, Ybf, labels, stats, stats + NROWS, stats + 2*NROWS, stats + 3*NROWS,
        partials + NTILE*NTILE);

    finalize_kernel<<<1, 256, 0, stream>>>(partials, out);
}

// Round 3
// 296.477 us; speedup vs baseline: 1.7986x; 1.2508x over previous
//
#include <hip/hip_runtime.h>
#include <hip/hip_bf16.h>
#include <stdint.h>
#include <math.h>

#define NROWS 8192
#define DIM   768
#define NTILE 64          // 8192/128
#define EPSV  1e-6f
#define NJN   (NTILE * NTILE)            // 4096 X-vs-Y tiles
#define NJJ   (NTILE * (NTILE + 1) / 2)  // 2080 upper-tri X-vs-X tiles
#define NBLK  (NJN + NJJ)

typedef __attribute__((ext_vector_type(8))) short short8;
typedef __attribute__((ext_vector_type(4))) float f32x4;

__device__ __forceinline__ ushort f2bf(float f) {
    union { float f; uint32_t u; } x; x.f = f;
    uint32_t r = x.u + 0x7fffu + ((x.u >> 16) & 1u);
    return (ushort)(r >> 16);
}

// async global->LDS, 16B per lane; LDS dest is wave-uniform base (+lane*16 by HW)
__device__ __forceinline__ void gload16(const void* g, void* l) {
    __builtin_amdgcn_global_load_lds(
        (const __attribute__((address_space(1))) void*)g,
        (__attribute__((address_space(3))) void*)l,
        16, 0, 0);
}

// ------- prep: bf16 convert into Z=[X;Y], folded row stats -------
// SXa[i]  = sx_i + 2*eps*rx_i                  (A-side, X rows only)
// TB[z]   = s_z  - 2*eps*r_z + D*eps*eps       (B-side, all Z rows)
__global__ __launch_bounds__(256)
void prep(const float* __restrict__ X, const float* __restrict__ Y,
          float* __restrict__ SXa, float* __restrict__ TB,
          ushort* __restrict__ Zbf) {
    int row = blockIdx.x;                  // 0..16383
    bool isX = row < NROWS;
    const float* p = (isX ? X : Y) + (size_t)(isX ? row : row - NROWS) * DIM;
    ushort* q = Zbf + (size_t)row * DIM;
    int t = threadIdx.x;
    float v0 = p[t], v1 = p[t + 256], v2 = p[t + 512];
    q[t] = f2bf(v0); q[t + 256] = f2bf(v1); q[t + 512] = f2bf(v2);
    float s = v0 + v1 + v2;
    float qs = v0*v0 + v1*v1 + v2*v2;
    #pragma unroll
    for (int o = 32; o; o >>= 1) { s += __shfl_down(s, o); qs += __shfl_down(qs, o); }
    __shared__ float sh[8];
    int wave = t >> 6, lane = t & 63;
    if (lane == 0) { sh[wave] = s; sh[4 + wave] = qs; }
    __syncthreads();
    if (t == 0) {
        float ss = sh[0]+sh[1]+sh[2]+sh[3];
        float qq = sh[4]+sh[5]+sh[6]+sh[7];
        if (isX) SXa[row] = qq + 2.f*EPSV*ss;
        TB[row] = qq - 2.f*EPSV*ss + (float)DIM*EPSV*EPSV;
    }
}

// ------- fused GEMM (m97 structure) + cheap loss epilogue -------
// One launch: blocks [0,4096) = JN tiles, [4096,6176) = JJ upper-tri tiles.
__global__ __launch_bounds__(256)
void gemm_loss(const ushort* __restrict__ Z, const int* __restrict__ labels,
               const float* __restrict__ SXa, const float* __restrict__ TB,
               float4* __restrict__ partials) {
    const int bid = blockIdx.x;
    const int t = threadIdx.x;

    int ti, tj, jrow0;                      // jrow0 = B-side row base in Z
    bool jj;
    if (bid < NJN) {
        jj = false; ti = bid >> 6; tj = bid & 63; jrow0 = NROWS + tj * 128;
    } else {
        jj = true;
        int u = bid - NJN;                  // 0..2079, upper-tri (ti<=tj)
        int t0 = (int)((129.0 - sqrt(129.0*129.0 - 8.0*(double)u)) * 0.5);
        if (t0 < 0) t0 = 0; if (t0 > 63) t0 = 63;
        while (t0 < 63 && (t0 + 1) * (129 - (t0 + 1)) / 2 <= u) ++t0;
        while (t0 > 0  && t0 * (129 - t0) / 2 > u) --t0;
        ti = t0; tj = ti + (u - ti * (129 - ti) / 2); jrow0 = tj * 128;
    }
    const int i0 = ti * 128;

    __shared__ __align__(16) ushort Asm[128 * 32];
    __shared__ __align__(16) ushort Bsm[128 * 32];
    __shared__ float red[4][4];

    const int wave = t >> 6, lane = t & 63;
    const int wr = wave >> 1, wc = wave & 1;

    const int grow = wave * 16 + (lane >> 2);
    const int gcol = (lane & 3) * 8;
    const ushort* pa0 = Z + (size_t)(i0 + grow)         * DIM + gcol;
    const ushort* pa1 = Z + (size_t)(i0 + grow + 64)    * DIM + gcol;
    const ushort* pb0 = Z + (size_t)(jrow0 + grow)      * DIM + gcol;
    const ushort* pb1 = Z + (size_t)(jrow0 + grow + 64) * DIM + gcol;
    ushort* la0 = Asm + wave * 512;
    ushort* la1 = Asm + (4 + wave) * 512;
    ushort* lb0 = Bsm + wave * 512;
    ushort* lb1 = Bsm + (4 + wave) * 512;

    const int mrow = lane & 15;
    const int kcol = (lane >> 4) * 8;

    f32x4 acc[4][4] = {};

    #pragma unroll 1
    for (int k0 = 0; k0 < DIM; k0 += 32) {
        __syncthreads();
        gload16(pa0 + k0, la0);
        gload16(pa1 + k0, la1);
        gload16(pb0 + k0, lb0);
        gload16(pb1 + k0, lb1);
        __syncthreads();

        short8 afr[4], bfr[4];
        #pragma unroll
        for (int mi = 0; mi < 4; ++mi)
            afr[mi] = *(const short8*)(Asm + (wr*64 + mi*16 + mrow) * 32 + kcol);
        #pragma unroll
        for (int ni = 0; ni < 4; ++ni)
            bfr[ni] = *(const short8*)(Bsm + (wc*64 + ni*16 + mrow) * 32 + kcol);
        #pragma unroll
        for (int mi = 0; mi < 4; ++mi)
            #pragma unroll
            for (int ni = 0; ni < 4; ++ni)
                acc[mi][ni] = __builtin_amdgcn_mfma_f32_16x16x32_bf16(
                    afr[mi], bfr[ni], acc[mi][ni], 0, 0, 0);
    }

    // -------- epilogue --------
    // local coords within the 128x128 tile:
    const int il = wr*64 + ((lane >> 4) << 2);   // + mi*16 + r
    const int jl = wc*64 + (lane & 15);          // + ni*16

    float sxv[4][4], tbv[4];
    #pragma unroll
    for (int mi = 0; mi < 4; ++mi)
        #pragma unroll
        for (int r = 0; r < 4; ++r)
            sxv[mi][r] = SXa[i0 + il + mi*16 + r];
    #pragma unroll
    for (int ni = 0; ni < 4; ++ni)
        tbv[ni] = TB[jrow0 + jl + ni*16];

    float pos = 0.f, neg = 0.f, cross = 0.f, cnt = 0.f;
    float mn = 1e30f;                        // min over valid neg/cross cands

    if (jj) {
        int labi[4][4], labj[4];
        #pragma unroll
        for (int mi = 0; mi < 4; ++mi)
            #pragma unroll
            for (int r = 0; r < 4; ++r)
                labi[mi][r] = labels[i0 + il + mi*16 + r];
        #pragma unroll
        for (int ni = 0; ni < 4; ++ni)
            labj[ni] = labels[jrow0 + jl + ni*16];
        const bool difftile = (ti != tj);
        #pragma unroll
        for (int mi = 0; mi < 4; ++mi)
            #pragma unroll
            for (int ni = 0; ni < 4; ++ni)
                #pragma unroll
                for (int r = 0; r < 4; ++r) {
                    float d2 = __builtin_fmaf(-2.f, acc[mi][ni][r],
                                              sxv[mi][r] + tbv[ni]);
                    bool lt   = difftile | ((il + mi*16 + r) < (jl + ni*16));
                    bool same = (labi[mi][r] == labj[ni]);
                    if (lt & same) { pos += fmaxf(d2, 0.f); cnt += 1.f; }
                    mn = fminf(mn, (lt & !same) ? d2 : 1e30f);
                }
    } else {
        #pragma unroll
        for (int mi = 0; mi < 4; ++mi)
            #pragma unroll
            for (int ni = 0; ni < 4; ++ni)
                #pragma unroll
                for (int r = 0; r < 4; ++r) {
                    float d2 = __builtin_fmaf(-2.f, acc[mi][ni][r],
                                              sxv[mi][r] + tbv[ni]);
                    mn = fminf(mn, d2);
                }
    }

    // rare exact path: only if some margin-active pair exists (never on this data)
    if (__any(mn < 1.f)) {
        int labi[4][4], labj[4];
        if (jj) {
            #pragma unroll
            for (int mi = 0; mi < 4; ++mi)
                #pragma unroll
                for (int r = 0; r < 4; ++r)
                    labi[mi][r] = labels[i0 + il + mi*16 + r];
            #pragma unroll
            for (int ni = 0; ni < 4; ++ni)
                labj[ni] = labels[jrow0 + jl + ni*16];
        }
        const bool difftile = (ti != tj);
        #pragma unroll
        for (int mi = 0; mi < 4; ++mi)
            #pragma unroll
            for (int ni = 0; ni < 4; ++ni)
                #pragma unroll
                for (int r = 0; r < 4; ++r) {
                    float d2 = __builtin_fmaf(-2.f, acc[mi][ni][r],
                                              sxv[mi][r] + tbv[ni]);
                    d2 = fmaxf(d2, 0.f);
                    float dist = sqrtf(fmaxf(d2, 1e-12f));
                    float m = fmaxf(1.f - dist, 0.f);
                    float s2 = m * m;
                    if (jj) {
                        bool lt   = difftile | ((il + mi*16 + r) < (jl + ni*16));
                        bool same = (labi[mi][r] == labj[ni]);
                        if (lt & !same) neg += s2;
                    } else {
                        cross += s2;
                    }
                }
    }

    #pragma unroll
    for (int o = 32; o; o >>= 1) {
        pos   += __shfl_down(pos, o);
        neg   += __shfl_down(neg, o);
        cross += __shfl_down(cross, o);
        cnt   += __shfl_down(cnt, o);
    }
    if (lane == 0) { red[wave][0] = pos; red[wave][1] = neg;
                     red[wave][2] = cross; red[wave][3] = cnt; }
    __syncthreads();
    if (t == 0) {
        float4 v;
        v.x = red[0][0]+red[1][0]+red[2][0]+red[3][0];
        v.y = red[0][1]+red[1][1]+red[2][1]+red[3][1];
        v.z = red[0][2]+red[1][2]+red[2][2]+red[3][2];
        v.w = red[0][3]+red[1][3]+red[2][3]+red[3][3];
        partials[bid] = v;
    }
}

// ---------------- final reduce ----------------
__global__ __launch_bounds__(256)
void finalize_kernel(const float4* __restrict__ partials, float* __restrict__ out) {
    int t = threadIdx.x;
    double p = 0, n = 0, c = 0, k = 0;
    for (int s = t; s < NBLK; s += 256) {
        float4 v = partials[s];
        p += v.x; n += v.y; c += v.z; k += v.w;
    }
    __shared__ double sh[256][4];
    sh[t][0] = p; sh[t][1] = n; sh[t][2] = c; sh[t][3] = k;
    __syncthreads();
    for (int o = 128; o; o >>= 1) {
        if (t < o) {
            sh[t][0] += sh[t+o][0]; sh[t][1] += sh[t+o][1];
            sh[t][2] += sh[t+o][2]; sh[t][3] += sh[t+o][3];
        }
        __syncthreads();
    }
    if (t == 0) {
        double npos = sh[0][3] < 1.0 ? 1.0 : sh[0][3];
        double total = (double)NROWS * (NROWS - 1) * 0.5;
        double nneg = total - sh[0][3]; if (nneg < 1.0) nneg = 1.0;
        double loss = sh[0][0] / npos + sh[0][1] / nneg
                    + sh[0][2] / ((double)NROWS * (double)NROWS);
        out[0] = (float)loss;
    }
}

extern "C" void kernel_launch(void* const* d_in, const int* in_sizes, int n_in,
                              void* d_out, int out_size, void* d_ws, size_t ws_size,
                              hipStream_t stream) {
    const float* X      = (const float*)d_in[0];
    const float* Y      = (const float*)d_in[1];
    const int*   labels = (const int*)d_in[2];
    float* out = (float*)d_out;
    char*  ws  = (char*)d_ws;

    // ws: partials (6176*16B=96.5KB, pad to 128KB) | SXa (32KB) | TB (64KB)
    //     | Zbf (16384*768*2B = 25.2MB)
    float4* partials = (float4*)ws;
    float*  SXa      = (float*)(ws + 128*1024);
    float*  TB       = (float*)(ws + 128*1024 + 32*1024);
    ushort* Zbf      = (ushort*)(ws + 256*1024);

    prep<<<2 * NROWS, 256, 0, stream>>>(X, Y, SXa, TB, Zbf);
    gemm_loss<<<NBLK, 256, 0, stream>>>(Zbf, labels, SXa, TB, partials);
    finalize_kernel<<<1, 256, 0, stream>>>(partials, out);
}

// Round 4
// 292.230 us; speedup vs baseline: 1.8248x; 1.0145x over previous
//
#include <hip/hip_runtime.h>
#include <hip/hip_bf16.h>
#include <stdint.h>
#include <math.h>

#define NROWS 8192
#define DIM   768
#define NKT   (DIM / 32)                 // 24 K-steps
#define NTILE 64                         // 8192/128
#define EPSV  1e-6f
#define NJN   (NTILE * NTILE)            // 4096 X-vs-Y tiles
#define NJJ   (NTILE * (NTILE + 1) / 2)  // 2080 upper-tri X-vs-X tiles
#define NBLK  (NJN + NJJ)                // 6176 = 8 * 772 (XCD-divisible)

typedef __attribute__((ext_vector_type(8))) short short8;
typedef __attribute__((ext_vector_type(4))) float f32x4;

__device__ __forceinline__ ushort f2bf(float f) {
    union { float f; uint32_t u; } x; x.f = f;
    uint32_t r = x.u + 0x7fffu + ((x.u >> 16) & 1u);
    return (ushort)(r >> 16);
}

// async global->LDS, 16B per lane; LDS dest is wave-uniform base (+lane*16 by HW)
__device__ __forceinline__ void gload16(const void* g, void* l) {
    __builtin_amdgcn_global_load_lds(
        (const __attribute__((address_space(1))) void*)g,
        (__attribute__((address_space(3))) void*)l,
        16, 0, 0);
}

// ------- prep: bf16 convert into Z=[X;Y], folded row stats -------
__global__ __launch_bounds__(256)
void prep(const float* __restrict__ X, const float* __restrict__ Y,
          float* __restrict__ SXa, float* __restrict__ TB,
          ushort* __restrict__ Zbf) {
    int row = blockIdx.x;                  // 0..16383
    bool isX = row < NROWS;
    const float* p = (isX ? X : Y) + (size_t)(isX ? row : row - NROWS) * DIM;
    ushort* q = Zbf + (size_t)row * DIM;
    int t = threadIdx.x;
    float v0 = p[t], v1 = p[t + 256], v2 = p[t + 512];
    q[t] = f2bf(v0); q[t + 256] = f2bf(v1); q[t + 512] = f2bf(v2);
    float s = v0 + v1 + v2;
    float qs = v0*v0 + v1*v1 + v2*v2;
    #pragma unroll
    for (int o = 32; o; o >>= 1) { s += __shfl_down(s, o); qs += __shfl_down(qs, o); }
    __shared__ float sh[8];
    int wave = t >> 6, lane = t & 63;
    if (lane == 0) { sh[wave] = s; sh[4 + wave] = qs; }
    __syncthreads();
    if (t == 0) {
        float ss = sh[0]+sh[1]+sh[2]+sh[3];
        float qq = sh[4]+sh[5]+sh[6]+sh[7];
        if (isX) SXa[row] = qq + 2.f*EPSV*ss;
        TB[row] = qq - 2.f*EPSV*ss + (float)DIM*EPSV*EPSV;
    }
}

// ------- fused GEMM (2-phase pipelined m97 structure) + loss epilogue -------
__global__ __launch_bounds__(256)
void gemm_loss(const ushort* __restrict__ Z, const int* __restrict__ labels,
               const float* __restrict__ SXa, const float* __restrict__ TB,
               float4* __restrict__ partials) {
    // bijective XCD swizzle: 6176 = 8 * 772
    const int bid = (blockIdx.x & 7) * (NBLK / 8) + (blockIdx.x >> 3);
    const int t = threadIdx.x;

    int ti, tj, jrow0;                      // jrow0 = B-side row base in Z
    bool jj;
    if (bid < NJN) {
        jj = false; ti = bid >> 6; tj = bid & 63; jrow0 = NROWS + tj * 128;
    } else {
        jj = true;
        int u = bid - NJN;                  // 0..2079, upper-tri (ti<=tj)
        int t0 = (int)((129.0 - sqrt(129.0*129.0 - 8.0*(double)u)) * 0.5);
        if (t0 < 0) t0 = 0; if (t0 > 63) t0 = 63;
        while (t0 < 63 && (t0 + 1) * (129 - (t0 + 1)) / 2 <= u) ++t0;
        while (t0 > 0  && t0 * (129 - t0) / 2 > u) --t0;
        ti = t0; tj = ti + (u - ti * (129 - ti) / 2); jrow0 = tj * 128;
    }
    const int i0 = ti * 128;

    // double-buffered linear LDS [2][128*32] bf16 per matrix
    __shared__ __align__(16) ushort Asm[2][128 * 32];
    __shared__ __align__(16) ushort Bsm[2][128 * 32];
    __shared__ float red[4][4];

    const int wave = t >> 6, lane = t & 63;
    const int wr = wave >> 1, wc = wave & 1;

    const int grow = wave * 16 + (lane >> 2);
    const int gcol = (lane & 3) * 8;
    const ushort* pa0 = Z + (size_t)(i0 + grow)         * DIM + gcol;
    const ushort* pa1 = Z + (size_t)(i0 + grow + 64)    * DIM + gcol;
    const ushort* pb0 = Z + (size_t)(jrow0 + grow)      * DIM + gcol;
    const ushort* pb1 = Z + (size_t)(jrow0 + grow + 64) * DIM + gcol;

    const int mrow = lane & 15;
    const int kcol = (lane >> 4) * 8;

    f32x4 acc[4][4] = {};

#define STAGE(buf, k0)                                   \
    do {                                                 \
        gload16(pa0 + (k0), &Asm[buf][wave * 512]);      \
        gload16(pa1 + (k0), &Asm[buf][(4 + wave) * 512]);\
        gload16(pb0 + (k0), &Bsm[buf][wave * 512]);      \
        gload16(pb1 + (k0), &Bsm[buf][(4 + wave) * 512]);\
    } while (0)

#define COMPUTE(buf)                                                          \
    do {                                                                      \
        short8 afr[4], bfr[4];                                                \
        _Pragma("unroll")                                                     \
        for (int mi = 0; mi < 4; ++mi)                                        \
            afr[mi] = *(const short8*)(&Asm[buf][(wr*64 + mi*16 + mrow)*32 + kcol]); \
        _Pragma("unroll")                                                     \
        for (int ni = 0; ni < 4; ++ni)                                        \
            bfr[ni] = *(const short8*)(&Bsm[buf][(wc*64 + ni*16 + mrow)*32 + kcol]); \
        _Pragma("unroll")                                                     \
        for (int mi = 0; mi < 4; ++mi)                                        \
            _Pragma("unroll")                                                 \
            for (int ni = 0; ni < 4; ++ni)                                    \
                acc[mi][ni] = __builtin_amdgcn_mfma_f32_16x16x32_bf16(        \
                    afr[mi], bfr[ni], acc[mi][ni], 0, 0, 0);                  \
    } while (0)

    // prologue: stage K-step 0 into buf0
    STAGE(0, 0);
    __syncthreads();                       // vmcnt(0) drain + barrier

    // 2-phase pipeline, ×2 unrolled so buffer index is compile-time
    #pragma unroll 1
    for (int kt = 0; kt < NKT; kt += 2) {
        STAGE(1, (kt + 1) * 32);           // issue next loads BEFORE compute
        COMPUTE(0);
        __syncthreads();                   // drains STAGE(1); buf0 reads done
        if (kt < NKT - 2) STAGE(0, (kt + 2) * 32);
        COMPUTE(1);
        __syncthreads();                   // drains STAGE(0); buf1 reads done
    }

    // -------- epilogue --------
    const int il = wr*64 + ((lane >> 4) << 2);   // + mi*16 + r
    const int jl = wc*64 + (lane & 15);          // + ni*16

    float sxv[4][4], tbv[4];
    #pragma unroll
    for (int mi = 0; mi < 4; ++mi)
        #pragma unroll
        for (int r = 0; r < 4; ++r)
            sxv[mi][r] = SXa[i0 + il + mi*16 + r];
    #pragma unroll
    for (int ni = 0; ni < 4; ++ni)
        tbv[ni] = TB[jrow0 + jl + ni*16];

    float pos = 0.f, neg = 0.f, cross = 0.f, cnt = 0.f;
    float mn = 1e30f;                        // min over valid neg/cross cands

    if (jj) {
        int labi[4][4], labj[4];
        #pragma unroll
        for (int mi = 0; mi < 4; ++mi)
            #pragma unroll
            for (int r = 0; r < 4; ++r)
                labi[mi][r] = labels[i0 + il + mi*16 + r];
        #pragma unroll
        for (int ni = 0; ni < 4; ++ni)
            labj[ni] = labels[jrow0 + jl + ni*16];
        const bool difftile = (ti != tj);
        #pragma unroll
        for (int mi = 0; mi < 4; ++mi)
            #pragma unroll
            for (int ni = 0; ni < 4; ++ni)
                #pragma unroll
                for (int r = 0; r < 4; ++r) {
                    float d2 = __builtin_fmaf(-2.f, acc[mi][ni][r],
                                              sxv[mi][r] + tbv[ni]);
                    bool lt   = difftile | ((il + mi*16 + r) < (jl + ni*16));
                    bool same = (labi[mi][r] == labj[ni]);
                    if (lt & same) { pos += fmaxf(d2, 0.f); cnt += 1.f; }
                    mn = fminf(mn, (lt & !same) ? d2 : 1e30f);
                }
    } else {
        #pragma unroll
        for (int mi = 0; mi < 4; ++mi)
            #pragma unroll
            for (int ni = 0; ni < 4; ++ni)
                #pragma unroll
                for (int r = 0; r < 4; ++r) {
                    float d2 = __builtin_fmaf(-2.f, acc[mi][ni][r],
                                              sxv[mi][r] + tbv[ni]);
                    mn = fminf(mn, d2);
                }
    }

    // rare exact path: only if some margin-active pair exists (never on this data)
    if (__any(mn < 1.f)) {
        int labi[4][4], labj[4];
        if (jj) {
            #pragma unroll
            for (int mi = 0; mi < 4; ++mi)
                #pragma unroll
                for (int r = 0; r < 4; ++r)
                    labi[mi][r] = labels[i0 + il + mi*16 + r];
            #pragma unroll
            for (int ni = 0; ni < 4; ++ni)
                labj[ni] = labels[jrow0 + jl + ni*16];
        }
        const bool difftile = (ti != tj);
        #pragma unroll
        for (int mi = 0; mi < 4; ++mi)
            #pragma unroll
            for (int ni = 0; ni < 4; ++ni)
                #pragma unroll
                for (int r = 0; r < 4; ++r) {
                    float d2 = __builtin_fmaf(-2.f, acc[mi][ni][r],
                                              sxv[mi][r] + tbv[ni]);
                    d2 = fmaxf(d2, 0.f);
                    float dist = sqrtf(fmaxf(d2, 1e-12f));
                    float m = fmaxf(1.f - dist, 0.f);
                    float s2 = m * m;
                    if (jj) {
                        bool lt   = difftile | ((il + mi*16 + r) < (jl + ni*16));
                        bool same = (labi[mi][r] == labj[ni]);
                        if (lt & !same) neg += s2;
                    } else {
                        cross += s2;
                    }
                }
    }

    #pragma unroll
    for (int o = 32; o; o >>= 1) {
        pos   += __shfl_down(pos, o);
        neg   += __shfl_down(neg, o);
        cross += __shfl_down(cross, o);
        cnt   += __shfl_down(cnt, o);
    }
    if (lane == 0) { red[wave][0] = pos; red[wave][1] = neg;
                     red[wave][2] = cross; red[wave][3] = cnt; }
    __syncthreads();
    if (t == 0) {
        float4 v;
        v.x = red[0][0]+red[1][0]+red[2][0]+red[3][0];
        v.y = red[0][1]+red[1][1]+red[2][1]+red[3][1];
        v.z = red[0][2]+red[1][2]+red[2][2]+red[3][2];
        v.w = red[0][3]+red[1][3]+red[2][3]+red[3][3];
        partials[bid] = v;
    }
#undef STAGE
#undef COMPUTE
}

// ---------------- final reduce ----------------
__global__ __launch_bounds__(256)
void finalize_kernel(const float4* __restrict__ partials, float* __restrict__ out) {
    int t = threadIdx.x;
    double p = 0, n = 0, c = 0, k = 0;
    for (int s = t; s < NBLK; s += 256) {
        float4 v = partials[s];
        p += v.x; n += v.y; c += v.z; k += v.w;
    }
    __shared__ double sh[256][4];
    sh[t][0] = p; sh[t][1] = n; sh[t][2] = c; sh[t][3] = k;
    __syncthreads();
    for (int o = 128; o; o >>= 1) {
        if (t < o) {
            sh[t][0] += sh[t+o][0]; sh[t][1] += sh[t+o][1];
            sh[t][2] += sh[t+o][2]; sh[t][3] += sh[t+o][3];
        }
        __syncthreads();
    }
    if (t == 0) {
        double npos = sh[0][3] < 1.0 ? 1.0 : sh[0][3];
        double total = (double)NROWS * (NROWS - 1) * 0.5;
        double nneg = total - sh[0][3]; if (nneg < 1.0) nneg = 1.0;
        double loss = sh[0][0] / npos + sh[0][1] / nneg
                    + sh[0][2] / ((double)NROWS * (double)NROWS);
        out[0] = (float)loss;
    }
}

extern "C" void kernel_launch(void* const* d_in, const int* in_sizes, int n_in,
                              void* d_out, int out_size, void* d_ws, size_t ws_size,
                              hipStream_t stream) {
    const float* X      = (const float*)d_in[0];
    const float* Y      = (const float*)d_in[1];
    const int*   labels = (const int*)d_in[2];
    float* out = (float*)d_out;
    char*  ws  = (char*)d_ws;

    float4* partials = (float4*)ws;
    float*  SXa      = (float*)(ws + 128*1024);
    float*  TB       = (float*)(ws + 128*1024 + 32*1024);
    ushort* Zbf      = (ushort*)(ws + 256*1024);

    prep<<<2 * NROWS, 256, 0, stream>>>(X, Y, SXa, TB, Zbf);
    gemm_loss<<<NBLK, 256, 0, stream>>>(Zbf, labels, SXa, TB, partials);
    finalize_kernel<<<1, 256, 0, stream>>>(partials, out);
}

// Round 5
// 156.784 us; speedup vs baseline: 3.4012x; 1.8639x over previous
//
#include <hip/hip_runtime.h>
#include <hip/hip_bf16.h>
#include <stdint.h>
#include <math.h>

#define NROWS 8192
#define DIM   768                        // elements per row (1 B each in fp8)
#define BK    128                        // K per step (fp8 bytes)
#define NKT   (DIM / BK)                 // 6 K-steps
#define NTILE 64                         // 8192/128
#define EPSV  1e-6f
#define NJN   (NTILE * NTILE)            // 4096 X-vs-Y tiles
#define NJJ   (NTILE * (NTILE + 1) / 2)  // 2080 upper-tri X-vs-X tiles
#define NBLK  (NJN + NJJ)                // 6176 = 8 * 772 (XCD-divisible)

typedef __attribute__((ext_vector_type(4))) int   int4v;
typedef __attribute__((ext_vector_type(8))) int   int8v;
typedef __attribute__((ext_vector_type(4))) float f32x4;
typedef unsigned char uchar;

// async global->LDS, 16B per lane; LDS dest is wave-uniform base (+lane*16 by HW)
__device__ __forceinline__ void gload16(const void* g, void* l) {
    __builtin_amdgcn_global_load_lds(
        (const __attribute__((address_space(1))) void*)g,
        (__attribute__((address_space(3))) void*)l,
        16, 0, 0);
}

// ------- prep: fp8-e4m3 convert into Z=[X;Y], folded row stats (exact fp32) -------
// SXa[i] = sx_i + 2*eps*rx_i   (A-side);  TB[z] = s_z - 2*eps*r_z + D*eps^2 (B-side)
__global__ __launch_bounds__(256)
void prep(const float* __restrict__ X, const float* __restrict__ Y,
          float* __restrict__ SXa, float* __restrict__ TB,
          uchar* __restrict__ Zf8) {
    int row = blockIdx.x;                  // 0..16383
    bool isX = row < NROWS;
    const float* p = (isX ? X : Y) + (size_t)(isX ? row : row - NROWS) * DIM;
    uint32_t* q = (uint32_t*)(Zf8 + (size_t)row * DIM);
    int t = threadIdx.x;
    float s = 0.f, qs = 0.f;
    if (t < 192) {                         // 192 * 4 = 768 elems
        float4 v = *(const float4*)(p + 4 * t);
        uint32_t u = __builtin_amdgcn_cvt_pk_fp8_f32(v.x, v.y, 0u, false);
        u = __builtin_amdgcn_cvt_pk_fp8_f32(v.z, v.w, u, true);
        q[t] = u;
        s  = v.x + v.y + v.z + v.w;
        qs = v.x*v.x + v.y*v.y + v.z*v.z + v.w*v.w;
    }
    #pragma unroll
    for (int o = 32; o; o >>= 1) { s += __shfl_down(s, o); qs += __shfl_down(qs, o); }
    __shared__ float sh[8];
    int wave = t >> 6, lane = t & 63;
    if (lane == 0) { sh[wave] = s; sh[4 + wave] = qs; }
    __syncthreads();
    if (t == 0) {
        float ss = sh[0]+sh[1]+sh[2]+sh[3];
        float qq = sh[4]+sh[5]+sh[6]+sh[7];
        if (isX) SXa[row] = qq + 2.f*EPSV*ss;
        TB[row] = qq - 2.f*EPSV*ss + (float)DIM*EPSV*EPSV;
    }
}

// ------- fused MX-fp8 GEMM (128x128 tile, BK=128, dbuf 2-phase) + loss epilogue -------
// LDS swizzle (both-sides involution): element (r,k) of a [128][128]B tile lives at
// byte r*128 + (k ^ ((r&7)<<4)).  global_load_lds writes linearly; the global SOURCE
// col is pre-swizzled; ds_read applies the same XOR.  16B blocks stay contiguous.
__global__ __launch_bounds__(256)
void gemm_loss(const uchar* __restrict__ Z, const int* __restrict__ labels,
               const float* __restrict__ SXa, const float* __restrict__ TB,
               float4* __restrict__ partials) {
    // bijective XCD swizzle: 6176 = 8 * 772
    const int bid = (blockIdx.x & 7) * (NBLK / 8) + (blockIdx.x >> 3);
    const int t = threadIdx.x;

    int ti, tj, jrow0;                      // jrow0 = B-side row base in Z
    bool jj;
    if (bid < NJN) {
        jj = false; ti = bid >> 6; tj = bid & 63; jrow0 = NROWS + tj * 128;
    } else {
        jj = true;
        int u = bid - NJN;                  // 0..2079, upper-tri (ti<=tj)
        int t0 = (int)((129.0 - sqrt(129.0*129.0 - 8.0*(double)u)) * 0.5);
        if (t0 < 0) t0 = 0; if (t0 > 63) t0 = 63;
        while (t0 < 63 && (t0 + 1) * (129 - (t0 + 1)) / 2 <= u) ++t0;
        while (t0 > 0  && t0 * (129 - t0) / 2 > u) --t0;
        ti = t0; tj = ti + (u - ti * (129 - ti) / 2); jrow0 = tj * 128;
    }
    const int i0 = ti * 128;

    __shared__ __align__(16) uchar Asm[2][128 * BK];   // 16 KB each buf
    __shared__ __align__(16) uchar Bsm[2][128 * BK];
    __shared__ float red[4][4];

    const int wave = t >> 6, lane = t & 63;
    const int wr = wave >> 1, wc = wave & 1;

    // staging: chunk qq covers LDS bytes [qq*4096 + t*16): row = qq*32 + (t>>3),
    // swizzled col = (t&7)*16; true global col = ((t&7)*16) ^ (((t>>3)&7)<<4)
    const int r0  = t >> 3;                               // 0..31
    const int cS  = ((t & 7) * 16) ^ (((t >> 3) & 7) << 4);
    const uchar* paS = Z + (size_t)(i0 + r0)    * DIM + cS;
    const uchar* pbS = Z + (size_t)(jrow0 + r0) * DIM + cS;

    f32x4 acc[4][4] = {};

#define STAGE(buf, kb)                                                        \
    do {                                                                      \
        _Pragma("unroll")                                                     \
        for (int qq = 0; qq < 4; ++qq) {                                      \
            gload16(paS + (size_t)qq*32*DIM + (kb), &Asm[buf][qq*4096 + wave*1024]); \
            gload16(pbS + (size_t)qq*32*DIM + (kb), &Bsm[buf][qq*4096 + wave*1024]); \
        }                                                                     \
    } while (0)

#define COMPUTE(buf)                                                          \
    do {                                                                      \
        int8v af[4], bf[4];                                                   \
        _Pragma("unroll")                                                     \
        for (int mi = 0; mi < 4; ++mi) {                                      \
            int rr = wr*64 + mi*16 + (lane & 15);                             \
            int sw = (rr & 7) << 4;                                           \
            int c0 = ((lane >> 4) * 32) ^ sw;                                 \
            int c1 = ((lane >> 4) * 32 + 16) ^ sw;                            \
            int4v lo = *(const int4v*)&Asm[buf][rr*128 + c0];                 \
            int4v hi = *(const int4v*)&Asm[buf][rr*128 + c1];                 \
            af[mi] = __builtin_shufflevector(lo, hi, 0,1,2,3,4,5,6,7);        \
        }                                                                     \
        _Pragma("unroll")                                                     \
        for (int ni = 0; ni < 4; ++ni) {                                      \
            int rr = wc*64 + ni*16 + (lane & 15);                             \
            int sw = (rr & 7) << 4;                                           \
            int c0 = ((lane >> 4) * 32) ^ sw;                                 \
            int c1 = ((lane >> 4) * 32 + 16) ^ sw;                            \
            int4v lo = *(const int4v*)&Bsm[buf][rr*128 + c0];                 \
            int4v hi = *(const int4v*)&Bsm[buf][rr*128 + c1];                 \
            bf[ni] = __builtin_shufflevector(lo, hi, 0,1,2,3,4,5,6,7);        \
        }                                                                     \
        _Pragma("unroll")                                                     \
        for (int mi = 0; mi < 4; ++mi)                                        \
            _Pragma("unroll")                                                 \
            for (int ni = 0; ni < 4; ++ni)                                    \
                acc[mi][ni] = __builtin_amdgcn_mfma_scale_f32_16x16x128_f8f6f4( \
                    af[mi], bf[ni], acc[mi][ni], 0, 0,                        \
                    0, 0x7F7F7F7Fu, 0, 0x7F7F7F7Fu);                          \
    } while (0)

    // prologue
    STAGE(0, 0);
    __syncthreads();                       // vmcnt(0) drain + barrier

    // 2-phase pipeline over 6 K-steps (x2 unrolled, compile-time buf index)
    #pragma unroll 1
    for (int kt = 0; kt < NKT; kt += 2) {
        STAGE(1, (kt + 1) * BK);           // issue next loads BEFORE compute
        COMPUTE(0);
        __syncthreads();                   // drains STAGE(1); buf0 reads done
        if (kt < NKT - 2) STAGE(0, (kt + 2) * BK);
        COMPUTE(1);
        __syncthreads();                   // drains STAGE(0); buf1 reads done
    }

    // -------- epilogue (C/D: col=lane&15, row=(lane>>4)*4+reg — shape-determined) ----
    const int il = wr*64 + ((lane >> 4) << 2);   // + mi*16 + r
    const int jl = wc*64 + (lane & 15);          // + ni*16

    float sxv[4][4], tbv[4];
    #pragma unroll
    for (int mi = 0; mi < 4; ++mi)
        #pragma unroll
        for (int r = 0; r < 4; ++r)
            sxv[mi][r] = SXa[i0 + il + mi*16 + r];
    #pragma unroll
    for (int ni = 0; ni < 4; ++ni)
        tbv[ni] = TB[jrow0 + jl + ni*16];

    float pos = 0.f, neg = 0.f, cross = 0.f, cnt = 0.f;
    float mn = 1e30f;                        // min over valid neg/cross cands

    if (jj) {
        int labi[4][4], labj[4];
        #pragma unroll
        for (int mi = 0; mi < 4; ++mi)
            #pragma unroll
            for (int r = 0; r < 4; ++r)
                labi[mi][r] = labels[i0 + il + mi*16 + r];
        #pragma unroll
        for (int ni = 0; ni < 4; ++ni)
            labj[ni] = labels[jrow0 - NROWS * 0 + jl + ni*16 - (jrow0 >= NROWS ? 0 : 0)];
        #pragma unroll
        for (int ni = 0; ni < 4; ++ni)
            labj[ni] = labels[tj * 128 + jl + ni*16];
        const bool difftile = (ti != tj);
        #pragma unroll
        for (int mi = 0; mi < 4; ++mi)
            #pragma unroll
            for (int ni = 0; ni < 4; ++ni)
                #pragma unroll
                for (int r = 0; r < 4; ++r) {
                    float d2 = __builtin_fmaf(-2.f, acc[mi][ni][r],
                                              sxv[mi][r] + tbv[ni]);
                    bool lt   = difftile | ((il + mi*16 + r) < (jl + ni*16));
                    bool same = (labi[mi][r] == labj[ni]);
                    if (lt & same) { pos += fmaxf(d2, 0.f); cnt += 1.f; }
                    mn = fminf(mn, (lt & !same) ? d2 : 1e30f);
                }
    } else {
        #pragma unroll
        for (int mi = 0; mi < 4; ++mi)
            #pragma unroll
            for (int ni = 0; ni < 4; ++ni)
                #pragma unroll
                for (int r = 0; r < 4; ++r) {
                    float d2 = __builtin_fmaf(-2.f, acc[mi][ni][r],
                                              sxv[mi][r] + tbv[ni]);
                    mn = fminf(mn, d2);
                }
    }

    // rare exact path: only if some margin-active pair exists (never on this data)
    if (__any(mn < 1.f)) {
        int labi[4][4], labj[4];
        if (jj) {
            #pragma unroll
            for (int mi = 0; mi < 4; ++mi)
                #pragma unroll
                for (int r = 0; r < 4; ++r)
                    labi[mi][r] = labels[i0 + il + mi*16 + r];
            #pragma unroll
            for (int ni = 0; ni < 4; ++ni)
                labj[ni] = labels[tj * 128 + jl + ni*16];
        }
        const bool difftile = (ti != tj);
        #pragma unroll
        for (int mi = 0; mi < 4; ++mi)
            #pragma unroll
            for (int ni = 0; ni < 4; ++ni)
                #pragma unroll
                for (int r = 0; r < 4; ++r) {
                    float d2 = __builtin_fmaf(-2.f, acc[mi][ni][r],
                                              sxv[mi][r] + tbv[ni]);
                    d2 = fmaxf(d2, 0.f);
                    float dist = sqrtf(fmaxf(d2, 1e-12f));
                    float m = fmaxf(1.f - dist, 0.f);
                    float s2 = m * m;
                    if (jj) {
                        bool lt   = difftile | ((il + mi*16 + r) < (jl + ni*16));
                        bool same = (labi[mi][r] == labj[ni]);
                        if (lt & !same) neg += s2;
                    } else {
                        cross += s2;
                    }
                }
    }

    #pragma unroll
    for (int o = 32; o; o >>= 1) {
        pos   += __shfl_down(pos, o);
        neg   += __shfl_down(neg, o);
        cross += __shfl_down(cross, o);
        cnt   += __shfl_down(cnt, o);
    }
    if (lane == 0) { red[wave][0] = pos; red[wave][1] = neg;
                     red[wave][2] = cross; red[wave][3] = cnt; }
    __syncthreads();
    if (t == 0) {
        float4 v;
        v.x = red[0][0]+red[1][0]+red[2][0]+red[3][0];
        v.y = red[0][1]+red[1][1]+red[2][1]+red[3][1];
        v.z = red[0][2]+red[1][2]+red[2][2]+red[3][2];
        v.w = red[0][3]+red[1][3]+red[2][3]+red[3][3];
        partials[bid] = v;
    }
#undef STAGE
#undef COMPUTE
}

// ---------------- final reduce ----------------
__global__ __launch_bounds__(256)
void finalize_kernel(const float4* __restrict__ partials, float* __restrict__ out) {
    int t = threadIdx.x;
    double p = 0, n = 0, c = 0, k = 0;
    for (int s = t; s < NBLK; s += 256) {
        float4 v = partials[s];
        p += v.x; n += v.y; c += v.z; k += v.w;
    }
    __shared__ double sh[256][4];
    sh[t][0] = p; sh[t][1] = n; sh[t][2] = c; sh[t][3] = k;
    __syncthreads();
    for (int o = 128; o; o >>= 1) {
        if (t < o) {
            sh[t][0] += sh[t+o][0]; sh[t][1] += sh[t+o][1];
            sh[t][2] += sh[t+o][2]; sh[t][3] += sh[t+o][3];
        }
        __syncthreads();
    }
    if (t == 0) {
        double npos = sh[0][3] < 1.0 ? 1.0 : sh[0][3];
        double total = (double)NROWS * (NROWS - 1) * 0.5;
        double nneg = total - sh[0][3]; if (nneg < 1.0) nneg = 1.0;
        double loss = sh[0][0] / npos + sh[0][1] / nneg
                    + sh[0][2] / ((double)NROWS * (double)NROWS);
        out[0] = (float)loss;
    }
}

extern "C" void kernel_launch(void* const* d_in, const int* in_sizes, int n_in,
                              void* d_out, int out_size, void* d_ws, size_t ws_size,
                              hipStream_t stream) {
    const float* X      = (const float*)d_in[0];
    const float* Y      = (const float*)d_in[1];
    const int*   labels = (const int*)d_in[2];
    float* out = (float*)d_out;
    char*  ws  = (char*)d_ws;

    // ws: partials (128KB) | SXa (32KB) | TB (64KB) | Zf8 (16384*768 = 12.6MB)
    float4* partials = (float4*)ws;
    float*  SXa      = (float*)(ws + 128*1024);
    float*  TB       = (float*)(ws + 128*1024 + 32*1024);
    uchar*  Zf8      = (uchar*)(ws + 256*1024);

    prep<<<2 * NROWS, 256, 0, stream>>>(X, Y, SXa, TB, Zf8);
    gemm_loss<<<NBLK, 256, 0, stream>>>(Zf8, labels, SXa, TB, partials);
    finalize_kernel<<<1, 256, 0, stream>>>(partials, out);
}

// Round 6
// 145.771 us; speedup vs baseline: 3.6582x; 1.0756x over previous
//
#include <hip/hip_runtime.h>
#include <hip/hip_bf16.h>
#include <stdint.h>
#include <math.h>

#define NROWS  8192
#define DIM    768                        // elements per row (1 B each in fp8)
#define BK     128                        // K per step (fp8 bytes)
#define NKT    (DIM / BK)                 // 6 K-steps
#define BM     256
#define NTILE2 32                         // 8192/256
#define EPSV   1e-6f
#define NJN    (NTILE2 * NTILE2)           // 1024 X-vs-Y tiles
#define NJJ    (NTILE2 * (NTILE2 + 1) / 2) // 528 upper-tri X-vs-X tiles
#define NBLK   (NJN + NJJ)                 // 1552 = 8 * 194 (XCD-divisible)

typedef __attribute__((ext_vector_type(4))) int   int4v;
typedef __attribute__((ext_vector_type(8))) int   int8v;
typedef __attribute__((ext_vector_type(4))) float f32x4;
typedef unsigned char uchar;

// async global->LDS, 16B per lane; LDS dest is wave-uniform base (+lane*16 by HW)
__device__ __forceinline__ void gload16(const void* g, void* l) {
    __builtin_amdgcn_global_load_lds(
        (const __attribute__((address_space(1))) void*)g,
        (__attribute__((address_space(3))) void*)l,
        16, 0, 0);
}

// ------- prep: fp8-e4m3 convert into Z=[X;Y], folded row stats (exact fp32) -------
__global__ __launch_bounds__(256)
void prep(const float* __restrict__ X, const float* __restrict__ Y,
          float* __restrict__ SXa, float* __restrict__ TB,
          uchar* __restrict__ Zf8) {
    int row = blockIdx.x;                  // 0..16383
    bool isX = row < NROWS;
    const float* p = (isX ? X : Y) + (size_t)(isX ? row : row - NROWS) * DIM;
    uint32_t* q = (uint32_t*)(Zf8 + (size_t)row * DIM);
    int t = threadIdx.x;
    float s = 0.f, qs = 0.f;
    if (t < 192) {                         // 192 * 4 = 768 elems
        float4 v = *(const float4*)(p + 4 * t);
        uint32_t u = __builtin_amdgcn_cvt_pk_fp8_f32(v.x, v.y, 0u, false);
        u = __builtin_amdgcn_cvt_pk_fp8_f32(v.z, v.w, u, true);
        q[t] = u;
        s  = v.x + v.y + v.z + v.w;
        qs = v.x*v.x + v.y*v.y + v.z*v.z + v.w*v.w;
    }
    #pragma unroll
    for (int o = 32; o; o >>= 1) { s += __shfl_down(s, o); qs += __shfl_down(qs, o); }
    __shared__ float sh[8];
    int wave = t >> 6, lane = t & 63;
    if (lane == 0) { sh[wave] = s; sh[4 + wave] = qs; }
    __syncthreads();
    if (t == 0) {
        float ss = sh[0]+sh[1]+sh[2]+sh[3];
        float qq = sh[4]+sh[5]+sh[6]+sh[7];
        if (isX) SXa[row] = qq + 2.f*EPSV*ss;
        TB[row] = qq - 2.f*EPSV*ss + (float)DIM*EPSV*EPSV;
    }
}

// ------- fused MX-fp8 GEMM, 256x256 tile, 8 waves (2Mx4N), BK=128, 2-phase dbuf ----
// LDS swizzle (both-sides involution, verified r5): element (r,k) at byte
// r*128 + (k ^ ((r&7)<<4)); linear gload_lds dest + pre-swizzled global source.
__global__ __launch_bounds__(512, 2)
void gemm_loss(const uchar* __restrict__ Z, const int* __restrict__ labels,
               const float* __restrict__ SXa, const float* __restrict__ TB,
               float4* __restrict__ partials) {
    // bijective XCD swizzle: 1552 = 8 * 194
    const int bid = (blockIdx.x & 7) * (NBLK / 8) + (blockIdx.x >> 3);
    const int t = threadIdx.x;

    int ti, tj, jrow0;                      // jrow0 = B-side row base in Z
    bool jj;
    if (bid < NJN) {
        jj = false; ti = bid >> 5; tj = bid & 31; jrow0 = NROWS + tj * BM;
    } else {
        jj = true;
        int u = bid - NJN;                  // 0..527, upper-tri (ti<=tj), 32 rows
        int t0 = (int)((65.0 - sqrt(65.0*65.0 - 8.0*(double)u)) * 0.5);
        if (t0 < 0) t0 = 0; if (t0 > 31) t0 = 31;
        while (t0 < 31 && (t0 + 1) * (65 - (t0 + 1)) / 2 <= u) ++t0;
        while (t0 > 0  && t0 * (65 - t0) / 2 > u) --t0;
        ti = t0; tj = ti + (u - ti * (65 - ti) / 2); jrow0 = tj * BM;
    }
    const int i0 = ti * BM;

    __shared__ __align__(16) uchar Asm[2][BM * BK];   // 32 KB each buf
    __shared__ __align__(16) uchar Bsm[2][BM * BK];
    __shared__ float red[8][4];

    const int wave = t >> 6, lane = t & 63;
    const int wr = wave >> 2;               // 0..1 (M half)
    const int wc = wave & 3;                // 0..3 (N quarter)

    // staging: chunk c = wave + 8*qq covers LDS bytes [c*1024, c*1024+1024)
    // = rows 8c..8c+7; lane l -> row 8c+(l>>3), swz col (l&7)*16;
    // true global col = ((l&7)*16) ^ ((l>>3)<<4)   (row&7 == l>>3)
    const int cS = ((lane & 7) * 16) ^ ((lane >> 3) << 4);
    const uchar* paS = Z + (size_t)(i0 + 8*wave + (lane >> 3))    * DIM + cS;
    const uchar* pbS = Z + (size_t)(jrow0 + 8*wave + (lane >> 3)) * DIM + cS;

    const int lrow = lane & 15;
    const int kg   = (lane >> 4) * 32;      // 32-byte K-group per lane quarter

    f32x4 acc[8][4] = {};

#define STAGE(buf, kb)                                                         \
    do {                                                                       \
        _Pragma("unroll")                                                      \
        for (int qq = 0; qq < 4; ++qq) {                                       \
            gload16(paS + (size_t)qq*64*DIM + (kb), &Asm[buf][(wave + 8*qq)*1024]); \
            gload16(pbS + (size_t)qq*64*DIM + (kb), &Bsm[buf][(wave + 8*qq)*1024]); \
        }                                                                      \
    } while (0)

#define COMPUTE(buf)                                                           \
    do {                                                                       \
        int8v bfr[4];                                                          \
        _Pragma("unroll")                                                      \
        for (int ni = 0; ni < 4; ++ni) {                                       \
            int rr = wc*64 + ni*16 + lrow;                                     \
            int sw = (rr & 7) << 4;                                            \
            int4v lo = *(const int4v*)&Bsm[buf][rr*128 + (kg ^ sw)];           \
            int4v hi = *(const int4v*)&Bsm[buf][rr*128 + ((kg + 16) ^ sw)];    \
            bfr[ni] = __builtin_shufflevector(lo, hi, 0,1,2,3,4,5,6,7);        \
        }                                                                      \
        _Pragma("unroll")                                                      \
        for (int mi = 0; mi < 8; ++mi) {                                       \
            int rr = wr*128 + mi*16 + lrow;                                    \
            int sw = (rr & 7) << 4;                                            \
            int4v lo = *(const int4v*)&Asm[buf][rr*128 + (kg ^ sw)];           \
            int4v hi = *(const int4v*)&Asm[buf][rr*128 + ((kg + 16) ^ sw)];    \
            int8v afr = __builtin_shufflevector(lo, hi, 0,1,2,3,4,5,6,7);      \
            _Pragma("unroll")                                                  \
            for (int ni = 0; ni < 4; ++ni)                                     \
                acc[mi][ni] = __builtin_amdgcn_mfma_scale_f32_16x16x128_f8f6f4( \
                    afr, bfr[ni], acc[mi][ni], 0, 0,                           \
                    0, 0x7F7F7F7Fu, 0, 0x7F7F7F7Fu);                           \
        }                                                                      \
    } while (0)

    // prologue
    STAGE(0, 0);
    __syncthreads();                       // vmcnt(0) drain + barrier

    // 2-phase pipeline over 6 K-steps (x2 unrolled, compile-time buf index)
    #pragma unroll 1
    for (int kt = 0; kt < NKT; kt += 2) {
        STAGE(1, (kt + 1) * BK);           // issue next loads BEFORE compute
        COMPUTE(0);
        __syncthreads();                   // drains STAGE(1); buf0 reads done
        if (kt < NKT - 2) STAGE(0, (kt + 2) * BK);
        COMPUTE(1);
        __syncthreads();                   // drains STAGE(0); buf1 reads done
    }

    // -------- epilogue (C/D: col=lane&15, row=(lane>>4)*4+reg) --------
    const int il = wr*128 + ((lane >> 4) << 2);  // + mi*16 + r
    const int jl = wc*64 + (lane & 15);          // + ni*16

    float tbv[4];
    #pragma unroll
    for (int ni = 0; ni < 4; ++ni)
        tbv[ni] = TB[jrow0 + jl + ni*16];

    float pos = 0.f, neg = 0.f, cross = 0.f, cnt = 0.f;
    float mn = 1e30f;                        // min over valid neg/cross cands

    if (jj) {
        int labj[4];
        #pragma unroll
        for (int ni = 0; ni < 4; ++ni)
            labj[ni] = labels[tj * BM + jl + ni*16];
        const bool difftile = (ti != tj);
        #pragma unroll
        for (int mi = 0; mi < 8; ++mi) {
            float4 sx4 = *(const float4*)&SXa[i0 + il + mi*16];
            int4   la4 = *(const int4*)&labels[i0 + il + mi*16];
            float sxr[4] = {sx4.x, sx4.y, sx4.z, sx4.w};
            int   lar[4] = {la4.x, la4.y, la4.z, la4.w};
            #pragma unroll
            for (int ni = 0; ni < 4; ++ni)
                #pragma unroll
                for (int r = 0; r < 4; ++r) {
                    float d2 = __builtin_fmaf(-2.f, acc[mi][ni][r],
                                              sxr[r] + tbv[ni]);
                    bool lt   = difftile | ((il + mi*16 + r) < (jl + ni*16));
                    bool same = (lar[r] == labj[ni]);
                    if (lt & same) { pos += fmaxf(d2, 0.f); cnt += 1.f; }
                    mn = fminf(mn, (lt & !same) ? d2 : 1e30f);
                }
        }
    } else {
        #pragma unroll
        for (int mi = 0; mi < 8; ++mi) {
            float4 sx4 = *(const float4*)&SXa[i0 + il + mi*16];
            float sxr[4] = {sx4.x, sx4.y, sx4.z, sx4.w};
            #pragma unroll
            for (int ni = 0; ni < 4; ++ni)
                #pragma unroll
                for (int r = 0; r < 4; ++r) {
                    float d2 = __builtin_fmaf(-2.f, acc[mi][ni][r],
                                              sxr[r] + tbv[ni]);
                    mn = fminf(mn, d2);
                }
        }
    }

    // rare exact path: only if some margin-active pair exists (never on this data)
    if (__any(mn < 1.f)) {
        int labj[4] = {0,0,0,0};
        if (jj)
            #pragma unroll
            for (int ni = 0; ni < 4; ++ni)
                labj[ni] = labels[tj * BM + jl + ni*16];
        const bool difftile = (ti != tj);
        #pragma unroll
        for (int mi = 0; mi < 8; ++mi) {
            float4 sx4 = *(const float4*)&SXa[i0 + il + mi*16];
            float sxr[4] = {sx4.x, sx4.y, sx4.z, sx4.w};
            int lar[4] = {0,0,0,0};
            if (jj) {
                int4 la4 = *(const int4*)&labels[i0 + il + mi*16];
                lar[0]=la4.x; lar[1]=la4.y; lar[2]=la4.z; lar[3]=la4.w;
            }
            #pragma unroll
            for (int ni = 0; ni < 4; ++ni)
                #pragma unroll
                for (int r = 0; r < 4; ++r) {
                    float d2 = __builtin_fmaf(-2.f, acc[mi][ni][r],
                                              sxr[r] + tbv[ni]);
                    d2 = fmaxf(d2, 0.f);
                    float dist = sqrtf(fmaxf(d2, 1e-12f));
                    float m = fmaxf(1.f - dist, 0.f);
                    float s2 = m * m;
                    if (jj) {
                        bool lt   = difftile | ((il + mi*16 + r) < (jl + ni*16));
                        bool same = (lar[r] == labj[ni]);
                        if (lt & !same) neg += s2;
                    } else {
                        cross += s2;
                    }
                }
        }
    }

    #pragma unroll
    for (int o = 32; o; o >>= 1) {
        pos   += __shfl_down(pos, o);
        neg   += __shfl_down(neg, o);
        cross += __shfl_down(cross, o);
        cnt   += __shfl_down(cnt, o);
    }
    if (lane == 0) { red[wave][0] = pos; red[wave][1] = neg;
                     red[wave][2] = cross; red[wave][3] = cnt; }
    __syncthreads();
    if (t == 0) {
        float4 v = {0.f, 0.f, 0.f, 0.f};
        #pragma unroll
        for (int w = 0; w < 8; ++w) {
            v.x += red[w][0]; v.y += red[w][1];
            v.z += red[w][2]; v.w += red[w][3];
        }
        partials[bid] = v;
    }
#undef STAGE
#undef COMPUTE
}

// ---------------- final reduce ----------------
__global__ __launch_bounds__(256)
void finalize_kernel(const float4* __restrict__ partials, float* __restrict__ out) {
    int t = threadIdx.x;
    double p = 0, n = 0, c = 0, k = 0;
    for (int s = t; s < NBLK; s += 256) {
        float4 v = partials[s];
        p += v.x; n += v.y; c += v.z; k += v.w;
    }
    __shared__ double sh[256][4];
    sh[t][0] = p; sh[t][1] = n; sh[t][2] = c; sh[t][3] = k;
    __syncthreads();
    for (int o = 128; o; o >>= 1) {
        if (t < o) {
            sh[t][0] += sh[t+o][0]; sh[t][1] += sh[t+o][1];
            sh[t][2] += sh[t+o][2]; sh[t][3] += sh[t+o][3];
        }
        __syncthreads();
    }
    if (t == 0) {
        double npos = sh[0][3] < 1.0 ? 1.0 : sh[0][3];
        double total = (double)NROWS * (NROWS - 1) * 0.5;
        double nneg = total - sh[0][3]; if (nneg < 1.0) nneg = 1.0;
        double loss = sh[0][0] / npos + sh[0][1] / nneg
                    + sh[0][2] / ((double)NROWS * (double)NROWS);
        out[0] = (float)loss;
    }
}

extern "C" void kernel_launch(void* const* d_in, const int* in_sizes, int n_in,
                              void* d_out, int out_size, void* d_ws, size_t ws_size,
                              hipStream_t stream) {
    const float* X      = (const float*)d_in[0];
    const float* Y      = (const float*)d_in[1];
    const int*   labels = (const int*)d_in[2];
    float* out = (float*)d_out;
    char*  ws  = (char*)d_ws;

    // ws: partials (128KB) | SXa (32KB) | TB (64KB) | Zf8 (16384*768 = 12.6MB)
    float4* partials = (float4*)ws;
    float*  SXa      = (float*)(ws + 128*1024);
    float*  TB       = (float*)(ws + 128*1024 + 32*1024);
    uchar*  Zf8      = (uchar*)(ws + 256*1024);

    prep<<<2 * NROWS, 256, 0, stream>>>(X, Y, SXa, TB, Zf8);
    gemm_loss<<<NBLK, 512, 0, stream>>>(Zf8, labels, SXa, TB, partials);
    finalize_kernel<<<1, 256, 0, stream>>>(partials, out);
}

// Round 7
// 140.210 us; speedup vs baseline: 3.8032x; 1.0397x over previous
//
#include <hip/hip_runtime.h>
#include <hip/hip_bf16.h>
#include <stdint.h>
#include <math.h>

#define NROWS  8192
#define DIM    768                        // elements per row (1 B each in fp8)
#define BK     128                        // K per step (fp8 bytes)
#define NKT    (DIM / BK)                 // 6 K-steps
#define BM     256
#define NTILE2 32                         // 8192/256
#define EPSV   1e-6f
#define NJN    (NTILE2 * NTILE2)           // 1024 X-vs-Y tiles
#define NJJ    (NTILE2 * (NTILE2 + 1) / 2) // 528 upper-tri X-vs-X tiles
#define NBLK   (NJN + NJJ)                 // 1552 = 8 * 194 (XCD-divisible)

typedef __attribute__((ext_vector_type(4))) int   int4v;
typedef __attribute__((ext_vector_type(8))) int   int8v;
typedef __attribute__((ext_vector_type(4))) float f32x4;
typedef unsigned char uchar;

// async global->LDS, 16B per lane; LDS dest is wave-uniform base (+lane*16 by HW)
__device__ __forceinline__ void gload16(const void* g, void* l) {
    __builtin_amdgcn_global_load_lds(
        (const __attribute__((address_space(1))) void*)g,
        (__attribute__((address_space(3))) void*)l,
        16, 0, 0);
}

// ------- prep: fp8-e4m3 convert into Z=[X;Y], folded row stats (exact fp32) -------
__global__ __launch_bounds__(256)
void prep(const float* __restrict__ X, const float* __restrict__ Y,
          float* __restrict__ SXa, float* __restrict__ TB,
          uchar* __restrict__ Zf8) {
    int row = blockIdx.x;                  // 0..16383
    bool isX = row < NROWS;
    const float* p = (isX ? X : Y) + (size_t)(isX ? row : row - NROWS) * DIM;
    uint32_t* q = (uint32_t*)(Zf8 + (size_t)row * DIM);
    int t = threadIdx.x;
    float s = 0.f, qs = 0.f;
    if (t < 192) {                         // 192 * 4 = 768 elems
        float4 v = *(const float4*)(p + 4 * t);
        uint32_t u = __builtin_amdgcn_cvt_pk_fp8_f32(v.x, v.y, 0u, false);
        u = __builtin_amdgcn_cvt_pk_fp8_f32(v.z, v.w, u, true);
        q[t] = u;
        s  = v.x + v.y + v.z + v.w;
        qs = v.x*v.x + v.y*v.y + v.z*v.z + v.w*v.w;
    }
    #pragma unroll
    for (int o = 32; o; o >>= 1) { s += __shfl_down(s, o); qs += __shfl_down(qs, o); }
    __shared__ float sh[8];
    int wave = t >> 6, lane = t & 63;
    if (lane == 0) { sh[wave] = s; sh[4 + wave] = qs; }
    __syncthreads();
    if (t == 0) {
        float ss = sh[0]+sh[1]+sh[2]+sh[3];
        float qq = sh[4]+sh[5]+sh[6]+sh[7];
        if (isX) SXa[row] = qq + 2.f*EPSV*ss;
        TB[row] = qq - 2.f*EPSV*ss + (float)DIM*EPSV*EPSV;
    }
}

// ------- fused MX-fp8 GEMM, 256x256, 8 waves, BK=128, counted-vmcnt 2-deep dbuf ----
// LDS swizzle (both-sides involution, verified r5/r6): element (r,k) at byte
// r*128 + (k ^ ((r&7)<<4)); linear gload_lds dest + pre-swizzled global source.
__global__ __launch_bounds__(512, 2)
void gemm_loss(const uchar* __restrict__ Z, const int* __restrict__ labels,
               const float* __restrict__ SXa, const float* __restrict__ TB,
               float4* __restrict__ partials) {
    // bijective XCD swizzle: 1552 = 8 * 194
    const int bid = (blockIdx.x & 7) * (NBLK / 8) + (blockIdx.x >> 3);
    const int t = threadIdx.x;

    int ti, tj, jrow0;                      // jrow0 = B-side row base in Z
    bool jj;
    if (bid < NJN) {
        jj = false; ti = bid >> 5; tj = bid & 31; jrow0 = NROWS + tj * BM;
    } else {
        jj = true;
        int u = bid - NJN;                  // 0..527, upper-tri (ti<=tj), 32 rows
        int t0 = (int)((65.0 - sqrt(65.0*65.0 - 8.0*(double)u)) * 0.5);
        if (t0 < 0) t0 = 0; if (t0 > 31) t0 = 31;
        while (t0 < 31 && (t0 + 1) * (65 - (t0 + 1)) / 2 <= u) ++t0;
        while (t0 > 0  && t0 * (65 - t0) / 2 > u) --t0;
        ti = t0; tj = ti + (u - ti * (65 - ti) / 2); jrow0 = tj * BM;
    }
    const int i0 = ti * BM;

    __shared__ __align__(16) uchar Asm[2][BM * BK];   // 32 KB each buf
    __shared__ __align__(16) uchar Bsm[2][BM * BK];
    __shared__ float red[8][4];

    const int wave = t >> 6, lane = t & 63;
    const int wr = wave >> 2;               // 0..1 (M half)
    const int wc = wave & 3;                // 0..3 (N quarter)

    // staging: chunk c = wave + 8*qq covers LDS bytes [c*1024, c*1024+1024)
    // = rows 8c..8c+7; lane l -> row 8c+(l>>3), swz col (l&7)*16;
    // true global col = ((l&7)*16) ^ ((l>>3)<<4)   (row&7 == l>>3)
    const int cS = ((lane & 7) * 16) ^ ((lane >> 3) << 4);
    const uchar* paS = Z + (size_t)(i0 + 8*wave + (lane >> 3))    * DIM + cS;
    const uchar* pbS = Z + (size_t)(jrow0 + 8*wave + (lane >> 3)) * DIM + cS;

    const int lrow = lane & 15;
    const int kg   = (lane >> 4) * 32;      // 32-byte K-group per lane quarter

    f32x4 acc[8][4] = {};

#define STAGE(buf, kb)                                                         \
    do {                                                                       \
        _Pragma("unroll")                                                      \
        for (int qq = 0; qq < 4; ++qq) {                                       \
            gload16(paS + (size_t)qq*64*DIM + (kb), &Asm[buf][(wave + 8*qq)*1024]); \
            gload16(pbS + (size_t)qq*64*DIM + (kb), &Bsm[buf][(wave + 8*qq)*1024]); \
        }                                                                      \
    } while (0)

#define COMPUTE(buf)                                                           \
    do {                                                                       \
        int8v bfr[4];                                                          \
        _Pragma("unroll")                                                      \
        for (int ni = 0; ni < 4; ++ni) {                                       \
            int rr = wc*64 + ni*16 + lrow;                                     \
            int sw = (rr & 7) << 4;                                            \
            int4v lo = *(const int4v*)&Bsm[buf][rr*128 + (kg ^ sw)];           \
            int4v hi = *(const int4v*)&Bsm[buf][rr*128 + ((kg + 16) ^ sw)];    \
            bfr[ni] = __builtin_shufflevector(lo, hi, 0,1,2,3,4,5,6,7);        \
        }                                                                      \
        __builtin_amdgcn_s_setprio(1);                                         \
        _Pragma("unroll")                                                      \
        for (int mi = 0; mi < 8; ++mi) {                                       \
            int rr = wr*128 + mi*16 + lrow;                                    \
            int sw = (rr & 7) << 4;                                            \
            int4v lo = *(const int4v*)&Asm[buf][rr*128 + (kg ^ sw)];           \
            int4v hi = *(const int4v*)&Asm[buf][rr*128 + ((kg + 16) ^ sw)];    \
            int8v afr = __builtin_shufflevector(lo, hi, 0,1,2,3,4,5,6,7);      \
            _Pragma("unroll")                                                  \
            for (int ni = 0; ni < 4; ++ni)                                     \
                acc[mi][ni] = __builtin_amdgcn_mfma_scale_f32_16x16x128_f8f6f4( \
                    afr, bfr[ni], acc[mi][ni], 0, 0,                           \
                    0, 0x7F7F7F7Fu, 0, 0x7F7F7F7Fu);                           \
        }                                                                      \
        __builtin_amdgcn_s_setprio(0);                                         \
    } while (0)

#define FENCE() asm volatile("" ::: "memory")
#define BAR()   do { FENCE(); __builtin_amdgcn_s_barrier(); FENCE(); } while (0)
#define VMW8()  asm volatile("s_waitcnt vmcnt(8)" ::: "memory")
#define VMW0()  asm volatile("s_waitcnt vmcnt(0)" ::: "memory")

    // prologue: two stages in flight
    STAGE(0, 0);
    STAGE(1, BK);
    VMW8(); BAR();                         // buf0 (k0) ready block-wide

    // steady state: counted-vmcnt 2-deep pipeline (kt = 0, 2)
    #pragma unroll 1
    for (int kt = 0; kt < NKT - 2; kt += 2) {
        COMPUTE(0);                        // k = kt
        BAR();                             // all waves done reading buf0
        STAGE(0, (kt + 2) * BK);
        VMW8(); BAR();                     // buf1 (kt+1) ready
        COMPUTE(1);                        // k = kt+1
        BAR();                             // all waves done reading buf1
        STAGE(1, (kt + 3) * BK);
        VMW8(); BAR();                     // buf0 (kt+2) ready
    }
    // tail: k = NKT-2, NKT-1 (no further stages)
    COMPUTE(0);
    VMW0(); BAR();                         // buf1 (NKT-1) ready block-wide
    COMPUTE(1);

    // -------- epilogue (C/D: col=lane&15, row=(lane>>4)*4+reg) --------
    const int il = wr*128 + ((lane >> 4) << 2);  // + mi*16 + r
    const int jl = wc*64 + (lane & 15);          // + ni*16

    float tbv[4];
    #pragma unroll
    for (int ni = 0; ni < 4; ++ni)
        tbv[ni] = TB[jrow0 + jl + ni*16];

    float pos = 0.f, neg = 0.f, cross = 0.f, cnt = 0.f;
    float mn = 1e30f;                        // min over valid neg/cross cands

    if (jj) {
        int labj[4];
        #pragma unroll
        for (int ni = 0; ni < 4; ++ni)
            labj[ni] = labels[tj * BM + jl + ni*16];
        const bool difftile = (ti != tj);
        #pragma unroll
        for (int mi = 0; mi < 8; ++mi) {
            float4 sx4 = *(const float4*)&SXa[i0 + il + mi*16];
            int4   la4 = *(const int4*)&labels[i0 + il + mi*16];
            float sxr[4] = {sx4.x, sx4.y, sx4.z, sx4.w};
            int   lar[4] = {la4.x, la4.y, la4.z, la4.w};
            #pragma unroll
            for (int ni = 0; ni < 4; ++ni)
                #pragma unroll
                for (int r = 0; r < 4; ++r) {
                    float d2 = __builtin_fmaf(-2.f, acc[mi][ni][r],
                                              sxr[r] + tbv[ni]);
                    bool lt   = difftile | ((il + mi*16 + r) < (jl + ni*16));
                    bool same = (lar[r] == labj[ni]);
                    if (lt & same) { pos += fmaxf(d2, 0.f); cnt += 1.f; }
                    mn = fminf(mn, (lt & !same) ? d2 : 1e30f);
                }
        }
    } else {
        #pragma unroll
        for (int mi = 0; mi < 8; ++mi) {
            float4 sx4 = *(const float4*)&SXa[i0 + il + mi*16];
            float sxr[4] = {sx4.x, sx4.y, sx4.z, sx4.w};
            #pragma unroll
            for (int ni = 0; ni < 4; ++ni)
                #pragma unroll
                for (int r = 0; r < 4; ++r) {
                    float d2 = __builtin_fmaf(-2.f, acc[mi][ni][r],
                                              sxr[r] + tbv[ni]);
                    mn = fminf(mn, d2);
                }
        }
    }

    // rare exact path: only if some margin-active pair exists (never on this data)
    if (__any(mn < 1.f)) {
        int labj[4] = {0,0,0,0};
        if (jj)
            #pragma unroll
            for (int ni = 0; ni < 4; ++ni)
                labj[ni] = labels[tj * BM + jl + ni*16];
        const bool difftile = (ti != tj);
        #pragma unroll
        for (int mi = 0; mi < 8; ++mi) {
            float4 sx4 = *(const float4*)&SXa[i0 + il + mi*16];
            float sxr[4] = {sx4.x, sx4.y, sx4.z, sx4.w};
            int lar[4] = {0,0,0,0};
            if (jj) {
                int4 la4 = *(const int4*)&labels[i0 + il + mi*16];
                lar[0]=la4.x; lar[1]=la4.y; lar[2]=la4.z; lar[3]=la4.w;
            }
            #pragma unroll
            for (int ni = 0; ni < 4; ++ni)
                #pragma unroll
                for (int r = 0; r < 4; ++r) {
                    float d2 = __builtin_fmaf(-2.f, acc[mi][ni][r],
                                              sxr[r] + tbv[ni]);
                    d2 = fmaxf(d2, 0.f);
                    float dist = sqrtf(fmaxf(d2, 1e-12f));
                    float m = fmaxf(1.f - dist, 0.f);
                    float s2 = m * m;
                    if (jj) {
                        bool lt   = difftile | ((il + mi*16 + r) < (jl + ni*16));
                        bool same = (lar[r] == labj[ni]);
                        if (lt & !same) neg += s2;
                    } else {
                        cross += s2;
                    }
                }
        }
    }

    #pragma unroll
    for (int o = 32; o; o >>= 1) {
        pos   += __shfl_down(pos, o);
        neg   += __shfl_down(neg, o);
        cross += __shfl_down(cross, o);
        cnt   += __shfl_down(cnt, o);
    }
    if (lane == 0) { red[wave][0] = pos; red[wave][1] = neg;
                     red[wave][2] = cross; red[wave][3] = cnt; }
    __syncthreads();
    if (t == 0) {
        float4 v = {0.f, 0.f, 0.f, 0.f};
        #pragma unroll
        for (int w = 0; w < 8; ++w) {
            v.x += red[w][0]; v.y += red[w][1];
            v.z += red[w][2]; v.w += red[w][3];
        }
        partials[bid] = v;
    }
#undef STAGE
#undef COMPUTE
#undef FENCE
#undef BAR
#undef VMW8
#undef VMW0
}

// ---------------- final reduce ----------------
__global__ __launch_bounds__(256)
void finalize_kernel(const float4* __restrict__ partials, float* __restrict__ out) {
    int t = threadIdx.x;
    double p = 0, n = 0, c = 0, k = 0;
    for (int s = t; s < NBLK; s += 256) {
        float4 v = partials[s];
        p += v.x; n += v.y; c += v.z; k += v.w;
    }
    __shared__ double sh[256][4];
    sh[t][0] = p; sh[t][1] = n; sh[t][2] = c; sh[t][3] = k;
    __syncthreads();
    for (int o = 128; o; o >>= 1) {
        if (t < o) {
            sh[t][0] += sh[t+o][0]; sh[t][1] += sh[t+o][1];
            sh[t][2] += sh[t+o][2]; sh[t][3] += sh[t+o][3];
        }
        __syncthreads();
    }
    if (t == 0) {
        double npos = sh[0][3] < 1.0 ? 1.0 : sh[0][3];
        double total = (double)NROWS * (NROWS - 1) * 0.5;
        double nneg = total - sh[0][3]; if (nneg < 1.0) nneg = 1.0;
        double loss = sh[0][0] / npos + sh[0][1] / nneg
                    + sh[0][2] / ((double)NROWS * (double)NROWS);
        out[0] = (float)loss;
    }
}

extern "C" void kernel_launch(void* const* d_in, const int* in_sizes, int n_in,
                              void* d_out, int out_size, void* d_ws, size_t ws_size,
                              hipStream_t stream) {
    const float* X      = (const float*)d_in[0];
    const float* Y      = (const float*)d_in[1];
    const int*   labels = (const int*)d_in[2];
    float* out = (float*)d_out;
    char*  ws  = (char*)d_ws;

    // ws: partials (128KB) | SXa (32KB) | TB (64KB) | Zf8 (16384*768 = 12.6MB)
    float4* partials = (float4*)ws;
    float*  SXa      = (float*)(ws + 128*1024);
    float*  TB       = (float*)(ws + 128*1024 + 32*1024);
    uchar*  Zf8      = (uchar*)(ws + 256*1024);

    prep<<<2 * NROWS, 256, 0, stream>>>(X, Y, SXa, TB, Zf8);
    gemm_loss<<<NBLK, 512, 0, stream>>>(Zf8, labels, SXa, TB, partials);
    finalize_kernel<<<1, 256, 0, stream>>>(partials, out);
}